// Round 1
// baseline (78.525 us; speedup 1.0000x reference)
//
#include <hip/hip_runtime.h>

#define BB 1024
#define DD 512
#define BT 16      // batch rows per block (kernel 1)
#define JT 128     // j columns per block
#define IT 32      // i-tile depth staged in LDS
#define NTILE (DD / IT)   // 16

// out[b] = ||x_dot[b]||^2 + t[b]^2,  t[b] = sum_{i,j} x_dot[b,i] W[i,j] x[b,j]
//
// Kernel 1: grid (BB/BT = 64, DD/JT = 4). Block (rg, jc) computes
//   ws[jc*BB + b] = sum_{j in chunk} x[b,j] * sum_i x_dot[b,i] W[i,j]
// Bilinear => partials over j-chunks simply add; square happens in kernel 2.
__global__ __launch_bounds__(256) void stm_partial_kernel(
    const float* __restrict__ x, const float* __restrict__ xdot,
    const float* __restrict__ W, float* __restrict__ ws_t) {
  __shared__ float xd_t[DD][BT];      // 32 KB, transposed x_dot tile [i][b]
  __shared__ float w_s[2][IT][JT];    // 2 x 16 KB double-buffered W tile

  const int tid = threadIdx.x;
  const int rg = blockIdx.x, jc = blockIdx.y;
  const int b0 = rg * BT, j0 = jc * JT;
  const int tb = tid >> 5;   // 0..7  -> rows b = 2*tb, 2*tb+1
  const int tj = tid & 31;   // 0..31 -> cols j = j0 + 4*tj .. +3

  // Stage x_dot transposed into LDS (one-time; write conflicts acceptable).
  {
    const int br = tid >> 4;   // 0..15
    const int c4 = tid & 15;   // 0..15
    const float4* src = (const float4*)(xdot + (size_t)(b0 + br) * DD);
#pragma unroll
    for (int cb = 0; cb < 8; ++cb) {
      float4 v = src[cb * 16 + c4];
      int c = (cb * 16 + c4) * 4;
      xd_t[c + 0][br] = v.x; xd_t[c + 1][br] = v.y;
      xd_t[c + 2][br] = v.z; xd_t[c + 3][br] = v.w;
    }
  }
  // Stage W tile 0 (rows 0..IT, cols j0..j0+JT). 1024 float4s / 256 threads.
  {
#pragma unroll
    for (int v = 0; v < 4; ++v) {
      int f4 = tid + v * 256;
      int ii = f4 >> 5, jj4 = f4 & 31;
      *((float4*)&w_s[0][ii][jj4 * 4]) =
          ((const float4*)(W + (size_t)ii * DD + j0))[jj4];
    }
  }
  __syncthreads();

  float acc[2][4] = {{0.f, 0.f, 0.f, 0.f}, {0.f, 0.f, 0.f, 0.f}};

  for (int t = 0; t < NTILE; ++t) {
    // Prefetch next W tile into registers (loads in flight during compute).
    float4 pre[4];
    if (t + 1 < NTILE) {
#pragma unroll
      for (int v = 0; v < 4; ++v) {
        int f4 = tid + v * 256;
        int ii = f4 >> 5, jj4 = f4 & 31;
        pre[v] = ((const float4*)(W + (size_t)((t + 1) * IT + ii) * DD + j0))[jj4];
      }
    }
    const int buf = t & 1;
#pragma unroll
    for (int ii = 0; ii < IT; ++ii) {
      const int i = t * IT + ii;
      float2 xd = *(const float2*)&xd_t[i][tb * 2];     // broadcast-friendly
      float4 w  = *(const float4*)&w_s[buf][ii][tj * 4];
      acc[0][0] += xd.x * w.x; acc[0][1] += xd.x * w.y;
      acc[0][2] += xd.x * w.z; acc[0][3] += xd.x * w.w;
      acc[1][0] += xd.y * w.x; acc[1][1] += xd.y * w.y;
      acc[1][2] += xd.y * w.z; acc[1][3] += xd.y * w.w;
    }
    if (t + 1 < NTILE) {
      // Buffer (t+1)&1 was last read in iter t-1; all waves are past that
      // (barrier at end of iter t-1), so store needs no extra barrier first.
#pragma unroll
      for (int v = 0; v < 4; ++v) {
        int f4 = tid + v * 256;
        int ii = f4 >> 5, jj4 = f4 & 31;
        *((float4*)&w_s[1 - buf][ii][jj4 * 4]) = pre[v];
      }
      __syncthreads();
    }
  }

  // Epilogue: sp[r] = sum over this thread's 4 j's of x[b,j] * y[b,j]
  float sp[2];
#pragma unroll
  for (int r = 0; r < 2; ++r) {
    const float4 xv = ((const float4*)(x + (size_t)(b0 + 2 * tb + r) * DD + j0))[tj];
    sp[r] = xv.x * acc[r][0] + xv.y * acc[r][1] +
            xv.z * acc[r][2] + xv.w * acc[r][3];
  }
  // Reduce across the 32 tj lanes (xor offsets < 32 stay within the group).
#pragma unroll
  for (int off = 16; off >= 1; off >>= 1) {
    sp[0] += __shfl_xor(sp[0], off);
    sp[1] += __shfl_xor(sp[1], off);
  }
  if (tj == 0) {
    ws_t[(size_t)jc * BB + b0 + 2 * tb + 0] = sp[0];
    ws_t[(size_t)jc * BB + b0 + 2 * tb + 1] = sp[1];
  }
}

// Kernel 2: one wave per batch row. out[b] = ||x_dot[b]||^2 + t[b]^2.
__global__ __launch_bounds__(256) void stm_final_kernel(
    const float* __restrict__ xdot, const float* __restrict__ ws_t,
    float* __restrict__ out) {
  const int tid = threadIdx.x;
  const int wv = tid >> 6, ln = tid & 63;
  const int b = blockIdx.x * 4 + wv;
  const float4* xd4 = (const float4*)(xdot + (size_t)b * DD);  // 128 float4/row
  float4 a = xd4[ln];
  float4 c = xd4[64 + ln];
  float n = a.x * a.x + a.y * a.y + a.z * a.z + a.w * a.w +
            c.x * c.x + c.y * c.y + c.z * c.z + c.w * c.w;
#pragma unroll
  for (int off = 32; off >= 1; off >>= 1) n += __shfl_xor(n, off);
  if (ln == 0) {
    float t = ws_t[b] + ws_t[BB + b] + ws_t[2 * BB + b] + ws_t[3 * BB + b];
    out[b] = n + t * t;
  }
}

extern "C" void kernel_launch(void* const* d_in, const int* in_sizes, int n_in,
                              void* d_out, int out_size, void* d_ws, size_t ws_size,
                              hipStream_t stream) {
  const float* x    = (const float*)d_in[0];
  const float* xdot = (const float*)d_in[1];
  const float* W    = (const float*)d_in[2];
  float* ws = (float*)d_ws;   // 4 * 1024 floats = 16 KB of partial t sums
  float* out = (float*)d_out;

  dim3 g1(BB / BT, DD / JT);  // (64, 4)
  stm_partial_kernel<<<g1, 256, 0, stream>>>(x, xdot, W, ws);
  stm_final_kernel<<<BB / 4, 256, 0, stream>>>(xdot, ws, out);
}

// Round 2
// 73.331 us; speedup vs baseline: 1.0708x; 1.0708x over previous
//
#include <hip/hip_runtime.h>

#define BB 1024
#define DD 512
#define BTILE 32     // batch rows per block
#define JTILE 128    // j columns per block
#define ICH 64       // i depth per block
// grid = (BB/BTILE, DD/JTILE, DD/ICH) = (32, 4, 8) = 1024 blocks, 256 thr
// 4 blocks/CU (LDS 40 KB/block), 4 waves/SIMD.

// out[b] = ||x_dot[b]||^2 + t[b]^2,  t[b] = sum_{i,j} x_dot[b,i] W[i,j] x[b,j]
// Block (rg,jc,ic) adds its (i,j)-rectangle partial of t[b] via atomicAdd.
__global__ __launch_bounds__(256, 4) void stm_main_kernel(
    const float* __restrict__ x, const float* __restrict__ xdot,
    const float* __restrict__ W, float* __restrict__ ws_t) {
  __shared__ float xd_t[ICH][BTILE];   // 8 KB, transposed x_dot chunk [i][b]
  __shared__ float w_s[ICH][JTILE];    // 32 KB W tile

  const int tid = threadIdx.x;
  const int b0 = blockIdx.x * BTILE;
  const int j0 = blockIdx.y * JTILE;
  const int i0 = blockIdx.z * ICH;
  const int tb = tid >> 5;   // 0..7  -> rows b0 + 4*tb .. +3
  const int tj = tid & 31;   // 0..31 -> cols j0 + 4*tj .. +3

  // Stage x_dot chunk transposed: rows b0..b0+31, cols i0..i0+63.
  // lane writes bank = row -> conflict-free scalar writes.
  {
    const int row = tid & 31;
    const int f4 = tid >> 5;             // 0..7
    const float4* src = (const float4*)(xdot + (size_t)(b0 + row) * DD + i0);
#pragma unroll
    for (int p = 0; p < 2; ++p) {
      const int c4 = f4 + p * 8;         // 0..15
      float4 v = src[c4];
      const int c = c4 * 4;
      xd_t[c + 0][row] = v.x; xd_t[c + 1][row] = v.y;
      xd_t[c + 2][row] = v.z; xd_t[c + 3][row] = v.w;
    }
  }
  // Stage W tile: rows i0..i0+63, cols j0..j0+127 (2048 float4 / 256 thr).
  {
#pragma unroll
    for (int v = 0; v < 8; ++v) {
      const int f4 = tid + v * 256;
      const int ii = f4 >> 5, jj4 = f4 & 31;
      *((float4*)&w_s[ii][jj4 * 4]) =
          ((const float4*)(W + (size_t)(i0 + ii) * DD + j0))[jj4];
    }
  }
  __syncthreads();

  // acc[r][c] = sum_i xd[b0+4tb+r, i] * W[i, j0+4tj+c]
  float acc[4][4] = {};
#pragma unroll
  for (int i = 0; i < ICH; ++i) {
    const float4 xd = *(const float4*)&xd_t[i][tb * 4];  // broadcast across tj
    const float4 w  = *(const float4*)&w_s[i][tj * 4];
    acc[0][0] += xd.x * w.x; acc[0][1] += xd.x * w.y;
    acc[0][2] += xd.x * w.z; acc[0][3] += xd.x * w.w;
    acc[1][0] += xd.y * w.x; acc[1][1] += xd.y * w.y;
    acc[1][2] += xd.y * w.z; acc[1][3] += xd.y * w.w;
    acc[2][0] += xd.z * w.x; acc[2][1] += xd.z * w.y;
    acc[2][2] += xd.z * w.z; acc[2][3] += xd.z * w.w;
    acc[3][0] += xd.w * w.x; acc[3][1] += xd.w * w.y;
    acc[3][2] += xd.w * w.z; acc[3][3] += xd.w * w.w;
  }

  // Partial t: contract with x over this thread's 4 j's, reduce over tj.
  float tp[4];
#pragma unroll
  for (int r = 0; r < 4; ++r) {
    const float4 xv =
        ((const float4*)(x + (size_t)(b0 + tb * 4 + r) * DD + j0))[tj];
    tp[r] = acc[r][0] * xv.x + acc[r][1] * xv.y +
            acc[r][2] * xv.z + acc[r][3] * xv.w;
  }
#pragma unroll
  for (int off = 16; off >= 1; off >>= 1) {
#pragma unroll
    for (int r = 0; r < 4; ++r) tp[r] += __shfl_xor(tp[r], off);
  }
  if (tj == 0) {
#pragma unroll
    for (int r = 0; r < 4; ++r)
      atomicAdd(ws_t + b0 + tb * 4 + r, tp[r]);
  }
}

// Kernel 2: one wave per batch row. out[b] = ||x_dot[b]||^2 + t[b]^2.
__global__ __launch_bounds__(256) void stm_final_kernel(
    const float* __restrict__ xdot, const float* __restrict__ ws_t,
    float* __restrict__ out) {
  const int tid = threadIdx.x;
  const int wv = tid >> 6, ln = tid & 63;
  const int b = blockIdx.x * 4 + wv;
  const float4* xd4 = (const float4*)(xdot + (size_t)b * DD);  // 128 f4/row
  float4 a = xd4[ln];
  float4 c = xd4[64 + ln];
  float n = a.x * a.x + a.y * a.y + a.z * a.z + a.w * a.w +
            c.x * c.x + c.y * c.y + c.z * c.z + c.w * c.w;
#pragma unroll
  for (int off = 32; off >= 1; off >>= 1) n += __shfl_xor(n, off);
  if (ln == 0) {
    const float t = ws_t[b];
    out[b] = n + t * t;
  }
}

extern "C" void kernel_launch(void* const* d_in, const int* in_sizes, int n_in,
                              void* d_out, int out_size, void* d_ws, size_t ws_size,
                              hipStream_t stream) {
  const float* x    = (const float*)d_in[0];
  const float* xdot = (const float*)d_in[1];
  const float* W    = (const float*)d_in[2];
  float* ws = (float*)d_ws;   // 1024 floats of t[b] accumulators
  float* out = (float*)d_out;

  // ws is re-poisoned to 0xAA before every launch -> zero the atomics region.
  hipMemsetAsync(ws, 0, BB * sizeof(float), stream);

  dim3 g1(BB / BTILE, DD / JTILE, DD / ICH);  // (32, 4, 8)
  stm_main_kernel<<<g1, 256, 0, stream>>>(x, xdot, W, ws);
  stm_final_kernel<<<BB / 4, 256, 0, stream>>>(xdot, ws, out);
}